// Round 3
// baseline (81.533 us; speedup 1.0000x reference)
//
#include <hip/hip_runtime.h>

// HungarianMatcher cost kernel.
// C[q,t] = sum_d mask[t,d]*|kp[q,d]-tgt[t,d]| + (pos-neg)[q, ids[t]]
// Q=16384, T=64, D=63, C=2 classes.
//
// Design: GEMM-style tiling. Block = 64q x 64t (all targets), 256 threads,
// thread tile 4q x 4t. LDS holds transposed [d][q] / [d][t] tiles with
// pitch 68 floats (17 float4) -> conflict-free b128 reads in the main loop.
// mask staged as 0/1 float so inner op is v_sub + v_fma(abs) = 2 VALU/elem.
//
// R3 PROBE: kernel launched TWICE (idempotent -> same output). dur_us delta
// vs R2 measures the true per-kernel time, which the rocprof top-5 cannot
// show (harness poison fills at ~40us occupy all slots). R2 showed unroll
// pragma = no-op, so either kernel is ~5us (model) or ~20us (hidden cost).

#define ALPHA 0.25f
#define EPS 1e-8f

constexpr int Q  = 16 * 1024;  // bs*nq
constexpr int T  = 64;
constexpr int D  = 63;
constexpr int QB = 64;         // q rows per block
constexpr int P  = 68;         // LDS pitch in floats (17 float4s)
constexpr int P4 = 17;

__device__ inline float focal_cost(float x) {
  float p   = 1.0f / (1.0f + __expf(-x));
  float pos = ALPHA * (1.0f - p) * (1.0f - p) * (-__logf(p + EPS));
  float neg = (1.0f - ALPHA) * p * p * (-__logf(1.0f - p + EPS));
  return pos - neg;
}

__global__ __launch_bounds__(256) void matcher_kernel(
    const float* __restrict__ logits,  // [Q,2]
    const float* __restrict__ kp,      // [Q,63]
    const float* __restrict__ tgt,     // [64,63]
    const int*   __restrict__ ids,     // [64]
    float* __restrict__ out)           // [Q,64]
{
  __shared__ __align__(16) float As[64 * P];  // [d][q]  (row d, col q)
  __shared__ __align__(16) float Bv[64 * P];  // [d][t]
  __shared__ __align__(16) float Bm[64 * P];  // [d][t] mask 0/1
  __shared__ int Ids[T];

  const int tid   = threadIdx.x;
  const int qbase = blockIdx.x * QB;

  // ---- stage A: transpose [q][d] -> [d][q]; global reads coalesced ----
  for (int i = tid; i < QB * D; i += 256) {
    int q = i / D;
    int d = i - q * D;
    As[d * P + q] = kp[(qbase + q) * D + d];
  }
  // ---- stage B: tgt values + visibility mask, transposed ----
  for (int i = tid; i < T * D; i += 256) {
    int t = i / D;
    int d = i - t * D;
    float v = tgt[t * D + d];
    Bv[d * P + t] = v;
    Bm[d * P + t] = (v > 0.0f) ? 1.0f : 0.0f;
  }
  if (tid < T) Ids[tid] = ids[tid];
  __syncthreads();

  const int qg = tid >> 4;  // 0..15 -> q = qbase + 4*qg + i
  const int tg = tid & 15;  // 0..15 -> t = 4*tg + j

  float4 acc0 = make_float4(0.f, 0.f, 0.f, 0.f);
  float4 acc1 = acc0, acc2 = acc0, acc3 = acc0;

  const float4* As4 = (const float4*)As;
  const float4* Bv4 = (const float4*)Bv;
  const float4* Bm4 = (const float4*)Bm;

#pragma unroll 7
  for (int d = 0; d < D; ++d) {
    float4 a  = As4[d * P4 + qg];
    float4 bv = Bv4[d * P4 + tg];
    float4 bm = Bm4[d * P4 + tg];
#define ROW(acc, av)                         \
    acc.x += bm.x * fabsf((av) - bv.x);      \
    acc.y += bm.y * fabsf((av) - bv.y);      \
    acc.z += bm.z * fabsf((av) - bv.z);      \
    acc.w += bm.w * fabsf((av) - bv.w);
    ROW(acc0, a.x)
    ROW(acc1, a.y)
    ROW(acc2, a.z)
    ROW(acc3, a.w)
#undef ROW
  }

  // ---- epilogue: add focal class cost, write coalesced float4 ----
  const int t0 = tg * 4;
  int id0 = min(max(Ids[t0 + 0], 0), 1);
  int id1 = min(max(Ids[t0 + 1], 0), 1);
  int id2 = min(max(Ids[t0 + 2], 0), 1);
  int id3 = min(max(Ids[t0 + 3], 0), 1);

  float4 accs[4] = {acc0, acc1, acc2, acc3};
#pragma unroll
  for (int i = 0; i < 4; ++i) {
    int q = qbase + qg * 4 + i;
    float cc0 = focal_cost(logits[q * 2 + 0]);
    float cc1 = focal_cost(logits[q * 2 + 1]);
    float cc[2] = {cc0, cc1};
    float4 r;
    r.x = accs[i].x + cc[id0];
    r.y = accs[i].y + cc[id1];
    r.z = accs[i].z + cc[id2];
    r.w = accs[i].w + cc[id3];
    *(float4*)&out[q * T + t0] = r;
  }
}

extern "C" void kernel_launch(void* const* d_in, const int* in_sizes, int n_in,
                              void* d_out, int out_size, void* d_ws, size_t ws_size,
                              hipStream_t stream) {
  const float* logits = (const float*)d_in[0];
  const float* kp     = (const float*)d_in[1];
  const float* tgt    = (const float*)d_in[2];
  const int*   ids    = (const int*)d_in[3];
  float* out = (float*)d_out;

  // R3 probe: two identical launches; dur delta vs R2 = per-kernel time.
  matcher_kernel<<<dim3(Q / QB), dim3(256), 0, stream>>>(logits, kp, tgt, ids, out);
  matcher_kernel<<<dim3(Q / QB), dim3(256), 0, stream>>>(logits, kp, tgt, ids, out);
}

// Round 4
// 73.797 us; speedup vs baseline: 1.1048x; 1.1048x over previous
//
#include <hip/hip_runtime.h>

// HungarianMatcher cost kernel.
// C[q,t] = sum_d mask[t,d]*|kp[q,d]-tgt[t,d]| + (pos-neg)[q, ids[t]]
// Q=16384, T=64, D=63, C=2 classes.
//
// R3 probe: kernel = 10.4us, harness floor = 60.7us (poison fill ~40us).
// R4: inner loop was LDS-issue-bound (3x ds_read_b128 x 4 waves x 12cyc =
// 144 cyc/iter/CU). Pack B as u32 per (t,d): high16 = bf16(tgt) (fp32 via
// single v_and), low16 = bf16(mask 0/1) (fp32 via single v_lshl). 2 b128
// reads/iter -> 96 cyc/iter bound (~2.5us). Focal class cost hoisted to
// staging (was 16x duplicated per qg + 8 global scalar loads/thread).
// bf16 B error ~0.1 on absmax 0.25, threshold 1.36 -> safe.

#define ALPHA 0.25f
#define EPS 1e-8f

constexpr int Q  = 16 * 1024;  // bs*nq
constexpr int T  = 64;
constexpr int D  = 63;
constexpr int QB = 64;         // q rows per block
constexpr int P  = 68;         // LDS pitch in words (17 x4-words)
constexpr int P4 = 17;

__device__ inline float focal_cost(float x) {
  float p   = 1.0f / (1.0f + __expf(-x));
  float pos = ALPHA * (1.0f - p) * (1.0f - p) * (-__logf(p + EPS));
  float neg = (1.0f - ALPHA) * p * p * (-__logf(1.0f - p + EPS));
  return pos - neg;
}

__device__ inline unsigned int to_bf16_rne(float v) {
  unsigned int x = __float_as_uint(v);
  return (x + 0x7FFFu + ((x >> 16) & 1u)) >> 16;
}

__global__ __launch_bounds__(256) void matcher_kernel(
    const float* __restrict__ logits,  // [Q,2]
    const float* __restrict__ kp,      // [Q,63]
    const float* __restrict__ tgt,     // [64,63]
    const int*   __restrict__ ids,     // [64]
    float* __restrict__ out)           // [Q,64]
{
  __shared__ __align__(16) float        As[64 * P];  // [d][q]
  __shared__ __align__(16) unsigned int Bp[64 * P];  // [d][t] packed bv|bm
  __shared__ float Lcc[QB * 2];                      // focal cost per (q,cls)
  __shared__ int   Ids[T];

  const int tid   = threadIdx.x;
  const int qbase = blockIdx.x * QB;

  // ---- stage A: vectorized read of the block's contiguous 16KB, transpose
  // [q][d] -> [d][q].  qbase*63*4 = blockIdx*16128, 16B-aligned. ----
  {
    const float4* src = (const float4*)(kp + qbase * D);
    for (int j = tid; j < QB * D / 4; j += 256) {
      float4 v = src[j];
      int i0 = 4 * j;
      float vv[4] = {v.x, v.y, v.z, v.w};
#pragma unroll
      for (int c = 0; c < 4; ++c) {
        int idx = i0 + c;
        int q = idx / D;
        int d = idx - q * D;
        As[d * P + q] = vv[c];
      }
    }
  }
  // ---- stage B: tgt values + visibility mask, bf16-packed, transposed ----
  {
    const float4* src = (const float4*)tgt;
    for (int j = tid; j < T * D / 4; j += 256) {
      float4 v = src[j];
      int i0 = 4 * j;
      float vv[4] = {v.x, v.y, v.z, v.w};
#pragma unroll
      for (int c = 0; c < 4; ++c) {
        int idx = i0 + c;
        int t = idx / D;
        int d = idx - t * D;
        unsigned int bv = to_bf16_rne(vv[c]);
        unsigned int bm = (vv[c] > 0.0f) ? 0x3F80u : 0x0000u;
        Bp[d * P + t] = (bv << 16) | bm;
      }
    }
  }
  // ---- stage focal: one eval per (q,cls), shared by all t-threads ----
  if (tid < QB * 2) Lcc[tid] = focal_cost(logits[qbase * 2 + tid]);
  if (tid < T) Ids[tid] = ids[tid];
  __syncthreads();

  const int qg = tid >> 4;  // 0..15 -> q = qbase + 4*qg + i
  const int tg = tid & 15;  // 0..15 -> t = 4*tg + j

  float4 acc0 = make_float4(0.f, 0.f, 0.f, 0.f);
  float4 acc1 = acc0, acc2 = acc0, acc3 = acc0;

  const float4* As4 = (const float4*)As;
  const uint4*  Bp4 = (const uint4*)Bp;

#pragma unroll 7
  for (int d = 0; d < D; ++d) {
    float4 a = As4[d * P4 + qg];
    uint4  w = Bp4[d * P4 + tg];
#define COL(acc_field, wf)                                   \
    {                                                        \
      float bv = __uint_as_float(wf & 0xFFFF0000u);          \
      float bm = __uint_as_float(wf << 16);                  \
      acc0.acc_field += bm * fabsf(a.x - bv);                \
      acc1.acc_field += bm * fabsf(a.y - bv);                \
      acc2.acc_field += bm * fabsf(a.z - bv);                \
      acc3.acc_field += bm * fabsf(a.w - bv);                \
    }
    COL(x, w.x)
    COL(y, w.y)
    COL(z, w.z)
    COL(w, w.w)
#undef COL
  }

  // ---- epilogue: add staged focal cost, write coalesced float4 ----
  const int t0 = tg * 4;
  int id0 = min(max(Ids[t0 + 0], 0), 1);
  int id1 = min(max(Ids[t0 + 1], 0), 1);
  int id2 = min(max(Ids[t0 + 2], 0), 1);
  int id3 = min(max(Ids[t0 + 3], 0), 1);

  float4 accs[4] = {acc0, acc1, acc2, acc3};
#pragma unroll
  for (int i = 0; i < 4; ++i) {
    int ql = qg * 4 + i;
    float cc[2] = {Lcc[ql * 2 + 0], Lcc[ql * 2 + 1]};
    float4 r;
    r.x = accs[i].x + cc[id0];
    r.y = accs[i].y + cc[id1];
    r.z = accs[i].z + cc[id2];
    r.w = accs[i].w + cc[id3];
    *(float4*)&out[(qbase + ql) * T + t0] = r;
  }
}

extern "C" void kernel_launch(void* const* d_in, const int* in_sizes, int n_in,
                              void* d_out, int out_size, void* d_ws, size_t ws_size,
                              hipStream_t stream) {
  const float* logits = (const float*)d_in[0];
  const float* kp     = (const float*)d_in[1];
  const float* tgt    = (const float*)d_in[2];
  const int*   ids    = (const int*)d_in[3];
  float* out = (float*)d_out;

  matcher_kernel<<<dim3(Q / QB), dim3(256), 0, stream>>>(logits, kp, tgt, ids, out);
}

// Round 5
// 70.628 us; speedup vs baseline: 1.1544x; 1.0449x over previous
//
#include <hip/hip_runtime.h>

// HungarianMatcher cost kernel.
// C[q,t] = sum_d mask[t,d]*|kp[q,d]-tgt[t,d]| + (pos-neg)[q, ids[t]]
// Q=16384, T=64, D=63, C=2 classes.
//
// R3 probe: kernel ~10.4us vs ~2-4us loop-throughput floor -> latency-bound
// at 1 wave/SIMD, not LDS-bound (R4 packed-B regression proved that).
// R5: (a) A read directly from global in the loop - per-wave 16-lane
// broadcast dwords, 4KB L1-resident column stream; kills the 16KB/block
// LDS transpose staging (cold-HBM serial latency + conflicted scatter).
// (b) fp32 Bv/Bm restored (no unpack VALU). (c) 512-thread blocks,
// tile 4q x 2t -> 8 waves/CU (2/SIMD) for 2x latency hiding.
// Inner: 2 VALU/elem (v_sub + v_fma with abs input modifier, mask as
// multiplicand), b64 B-reads (32 addrs, 2-way aliasing = free).

#define ALPHA 0.25f
#define EPS 1e-8f

constexpr int Q  = 16 * 1024;  // bs*nq
constexpr int T  = 64;
constexpr int D  = 63;
constexpr int QB = 64;         // q rows per block
constexpr int P  = 68;         // LDS pitch in floats (34 float2)
constexpr int P2 = 34;

__device__ inline float focal_cost(float x) {
  float p   = 1.0f / (1.0f + __expf(-x));
  float pos = ALPHA * (1.0f - p) * (1.0f - p) * (-__logf(p + EPS));
  float neg = (1.0f - ALPHA) * p * p * (-__logf(1.0f - p + EPS));
  return pos - neg;
}

__global__ __launch_bounds__(512) void matcher_kernel(
    const float* __restrict__ logits,  // [Q,2]
    const float* __restrict__ kp,      // [Q,63]
    const float* __restrict__ tgt,     // [64,63]
    const int*   __restrict__ ids,     // [64]
    float* __restrict__ out)           // [Q,64]
{
  __shared__ __align__(16) float Bv[64 * P];  // [d][t]
  __shared__ __align__(16) float Bm[64 * P];  // [d][t] mask 0/1
  __shared__ float Lcc[QB * 2];               // focal cost per (q,cls)
  __shared__ int   Ids[T];

  const int tid   = threadIdx.x;
  const int qbase = blockIdx.x * QB;

  // ---- stage B only: tgt values + visibility mask, transposed ----
  {
    const float4* src = (const float4*)tgt;
    for (int j = tid; j < T * D / 4; j += 512) {
      float4 v = src[j];
      int i0 = 4 * j;
      float vv[4] = {v.x, v.y, v.z, v.w};
#pragma unroll
      for (int c = 0; c < 4; ++c) {
        int idx = i0 + c;
        int t = idx / D;
        int d = idx - t * D;
        Bv[d * P + t] = vv[c];
        Bm[d * P + t] = (vv[c] > 0.0f) ? 1.0f : 0.0f;
      }
    }
  }
  // ---- stage focal: one eval per (q,cls) ----
  if (tid < QB * 2) Lcc[tid] = focal_cost(logits[qbase * 2 + tid]);
  if (tid < T) Ids[tid] = ids[tid];
  __syncthreads();

  const int qg = tid >> 5;  // 0..15 -> q = qbase + 4*qg + i
  const int tg = tid & 31;  // 0..31 -> t = 2*tg + j

  // A row pointers: 2 distinct per wave per i -> 32-lane broadcast loads,
  // L1-resident (64 rows x 64B line = 4KB working set, 16-iter line reuse).
  const float* __restrict__ r0 = kp + (qbase + qg * 4 + 0) * D;
  const float* __restrict__ r1 = kp + (qbase + qg * 4 + 1) * D;
  const float* __restrict__ r2 = kp + (qbase + qg * 4 + 2) * D;
  const float* __restrict__ r3 = kp + (qbase + qg * 4 + 3) * D;

  float2 acc0 = make_float2(0.f, 0.f);
  float2 acc1 = acc0, acc2 = acc0, acc3 = acc0;

  const float2* Bv2 = (const float2*)Bv;
  const float2* Bm2 = (const float2*)Bm;

#pragma unroll 7
  for (int d = 0; d < D; ++d) {
    float a0 = r0[d], a1 = r1[d], a2 = r2[d], a3 = r3[d];
    float2 bv = Bv2[d * P2 + tg];
    float2 bm = Bm2[d * P2 + tg];
    acc0.x += bm.x * fabsf(a0 - bv.x);
    acc0.y += bm.y * fabsf(a0 - bv.y);
    acc1.x += bm.x * fabsf(a1 - bv.x);
    acc1.y += bm.y * fabsf(a1 - bv.y);
    acc2.x += bm.x * fabsf(a2 - bv.x);
    acc2.y += bm.y * fabsf(a2 - bv.y);
    acc3.x += bm.x * fabsf(a3 - bv.x);
    acc3.y += bm.y * fabsf(a3 - bv.y);
  }

  // ---- epilogue: add staged focal cost, write coalesced float2 ----
  const int t0 = tg * 2;
  int id0 = min(max(Ids[t0 + 0], 0), 1);
  int id1 = min(max(Ids[t0 + 1], 0), 1);

  float2 accs[4] = {acc0, acc1, acc2, acc3};
#pragma unroll
  for (int i = 0; i < 4; ++i) {
    int ql = qg * 4 + i;
    float cc[2] = {Lcc[ql * 2 + 0], Lcc[ql * 2 + 1]};
    float2 r;
    r.x = accs[i].x + cc[id0];
    r.y = accs[i].y + cc[id1];
    *(float2*)&out[(qbase + ql) * T + t0] = r;
  }
}

extern "C" void kernel_launch(void* const* d_in, const int* in_sizes, int n_in,
                              void* d_out, int out_size, void* d_ws, size_t ws_size,
                              hipStream_t stream) {
  const float* logits = (const float*)d_in[0];
  const float* kp     = (const float*)d_in[1];
  const float* tgt    = (const float*)d_in[2];
  const int*   ids    = (const int*)d_in[3];
  float* out = (float*)d_out;

  matcher_kernel<<<dim3(Q / QB), dim3(512), 0, stream>>>(logits, kp, tgt, ids, out);
}